// Round 10
// baseline (164.604 us; speedup 1.0000x reference)
//
#include <hip/hip_runtime.h>
#include <hip/hip_bf16.h>

typedef __attribute__((ext_vector_type(8)))  __bf16 bf16x8;
typedef __attribute__((ext_vector_type(4)))  __bf16 bf16x4;
typedef __attribute__((ext_vector_type(16))) float  f32x16;
typedef __attribute__((ext_vector_type(4)))  float  f32x4;

#define B_    32
#define CIN   512
#define HID   256
#define HW    4096
#define NA    9
#define NCH   65      // 5*9 + 20
#define NPADC 96
#define BN    128     // spatial tile per block
#define M_    65536
#define NTOT  (B_*NA*HW)   // 1179648

// LDS-only barrier: drains DS ops, leaves global prefetches (vmcnt) in flight.
#define BAR() do {                                          \
    asm volatile("s_waitcnt lgkmcnt(0)" ::: "memory");      \
    __builtin_amdgcn_s_barrier();                           \
    __builtin_amdgcn_sched_barrier(0);                      \
} while (0)

// MEASUREMENT ROUND: kernel code is byte-identical to the R5 champion (92.2us).
// fused_mlp is launched TWICE (idempotent, deterministic); the bench delta vs
// 92.2us isolates fused_mlp's true duration without rocprof visibility.

// Workspace layout (bytes):
//   [0)         W1bt  bf16 [16][256][32]     262144  (K-tiled; L2-resident)
//   [262144)    W2p   bf16 [96][256]          49152  (rows >=65 zero)
//   [311296)    conf_d f32  [NTOT]          4718592
//   [5029888)   off_w  bf16 [NTOT][4]       9437184  (interleaved: 8B = 1-line gather)
//   [14467072)  cls_w  bf16 [B*HW][32]      8388608  (64B-aligned full-sector rows)

static __device__ __forceinline__ float sigf(float v) {
    return 1.f / (1.f + __expf(-v));
}

__global__ void prep_weights(const float* __restrict__ W1, const float* __restrict__ W2,
                             unsigned short* __restrict__ W1bt, unsigned short* __restrict__ W2p) {
    int i = blockIdx.x * 256 + threadIdx.x;
    if (i < 16*256*32) {
        int kt = i >> 13, o = (i >> 5) & 255, kk = i & 31;
        __bf16 h = (__bf16)W1[o*CIN + kt*32 + kk];
        W1bt[i] = __builtin_bit_cast(unsigned short, h);
    } else {
        int j = i - 16*256*32;
        if (j < NPADC*HID) {
            int o = j >> 8, c = j & 255;
            float v = (o < NCH) ? W2[o*HID + c] : 0.f;
            __bf16 h = (__bf16)v;
            W2p[j] = __builtin_bit_cast(unsigned short, h);
        }
    }
}

// 4 waves. GEMM1: h[256][128] = W1[256x512] @ F[512x128]; wave tile 64(M)x128(N).
// A direct from L2-resident W1bt, issued BEFORE B in the FIFO (A-wait never
// drains the HBM B-prefetch). B double-buffered in LDS, issue distance 2;
// ONE lgkm-only barrier/iter.
__launch_bounds__(256, 2)
__global__ void fused_mlp(const float* __restrict__ feat,
                          const float* __restrict__ b1,
                          const float* __restrict__ b2,
                          const unsigned short* __restrict__ W1bt,
                          const unsigned short* __restrict__ W2p,
                          float* __restrict__ conf_d,
                          unsigned short* __restrict__ off_w,
                          unsigned short* __restrict__ cls_w) {
    // union: [0,10240) Bs0 bf16[128][40]; [10240,20480) Bs1;
    //        after GEMM1: 64KB hT bf16 (col*512 + k*2) ^ ((col&7)<<4);
    //        after GEMM2: f32 out-stage [96][128] (48KB)
    __shared__ __align__(16) unsigned char smem[65536];

    const int tid  = threadIdx.x;
    const int w    = tid >> 6;
    const int lane = tid & 63;
    const int lr   = lane & 31;
    const int lh   = lane >> 5;
    const int bidx = blockIdx.x >> 5;
    const int hw0  = (blockIdx.x & 31) * BN;

    const float* fb = feat + (size_t)bidx * CIN * HW + hw0;

    const int sB  = tid & 127;        // B staging: spatial column
    const int kgB = tid >> 7;         // k-group 0/1 (handles kgB and kgB+2)

    f32x16 acc[2][4];
#pragma unroll
    for (int m = 0; m < 2; ++m)
#pragma unroll
        for (int n = 0; n < 4; ++n) acc[m][n] = (f32x16)0.f;

    float  pb[2][16];    // two in-flight feature tiles
    bf16x8 aw[2][4];     // two in-flight A-fragment sets: [set][kk*2+m]

    auto issueB = [&](int kt, int s) {
#pragma unroll
        for (int q = 0; q < 2; ++q) {
            const float* src = fb + (size_t)(kt*32 + (kgB + 2*q)*8) * HW + sB;
#pragma unroll
            for (int j = 0; j < 8; ++j) pb[s][q*8 + j] = src[(size_t)j * HW];
        }
    };
    auto issueA = [&](int kt, int s) {
#pragma unroll
        for (int kk = 0; kk < 2; ++kk)
#pragma unroll
            for (int m = 0; m < 2; ++m)
                aw[s][kk*2 + m] = *(const bf16x8*)(W1bt + kt*8192 + (64*w + 32*m + lr)*32 + kk*16 + lh*8);
    };
    auto storeB = [&](int s) {
        unsigned short* Bst = (unsigned short*)(smem + s*10240);
#pragma unroll
        for (int q = 0; q < 2; ++q) {
            bf16x8 v8;
#pragma unroll
            for (int j = 0; j < 8; ++j) v8[j] = (__bf16)pb[s][q*8 + j];
            *(bf16x8*)(Bst + sB*40 + (kgB + 2*q)*8) = v8;   // row=spatial, col=k
        }
    };

    // prologue: A(0), B(0), B(1) issued (A first in FIFO); store B(0)
    issueA(0, 0); issueB(0, 0); issueB(1, 1);
    storeB(0);               // waits vmcnt(16): drains A(0)+B(0), leaves B(1) in flight
    BAR();

#pragma unroll
    for (int kt = 0; kt < 16; ++kt) {
        const int cur = kt & 1, nxt = cur ^ 1;
        if (kt + 1 < 16) issueA(kt + 1, nxt);     // L2 A-frags first in queue
        if (kt + 2 < 16) issueB(kt + 2, cur);     // HBM prefetch behind them
        const unsigned short* Bst = (const unsigned short*)(smem + cur*10240);
#pragma unroll
        for (int kk = 0; kk < 2; ++kk) {
            bf16x8 a0 = aw[cur][kk*2 + 0];
            bf16x8 a1 = aw[cur][kk*2 + 1];
#pragma unroll
            for (int n = 0; n < 4; ++n) {
                bf16x8 bv = *(const bf16x8*)(Bst + (32*n + lr)*40 + kk*16 + lh*8);
                acc[0][n] = __builtin_amdgcn_mfma_f32_32x32x16_bf16(a0, bv, acc[0][n], 0, 0, 0);
                acc[1][n] = __builtin_amdgcn_mfma_f32_32x32x16_bf16(a1, bv, acc[1][n], 0, 0, 0);
            }
        }
        if (kt + 1 < 16) storeB(nxt);             // waits vmcnt(20): B(kt+1) only
        BAR();                                    // lgkm only; 20 loads stay in flight
    }

    // ---- epilogue 1: h = leaky(h + b1) -> hT in LDS (bf16, swizzled) ----
#pragma unroll
    for (int m = 0; m < 2; ++m)
#pragma unroll
        for (int n = 0; n < 4; ++n) {
            int col = 32*n + lr;
            unsigned cswz = (unsigned)((col & 7) << 4);
#pragma unroll
            for (int g = 0; g < 4; ++g) {
                int rbase = 64*w + 32*m + 8*g + 4*lh;        // h row (HID channel)
                f32x4 b1v = *(const f32x4*)(b1 + rbase);
                bf16x4 pk;
#pragma unroll
                for (int r = 0; r < 4; ++r) {
                    float v = acc[m][n][4*g + r] + b1v[r];
                    v = v > 0.f ? v : 0.01f * v;
                    pk[r] = (__bf16)v;
                }
                unsigned addr = (unsigned)(col*512 + rbase*2) ^ cswz;
                *(bf16x4*)(smem + addr) = pk;
            }
        }
    BAR();

    // ---- GEMM2: out[96][128] = W2p[96][256] @ h[256][128]; wave owns 32 cols ----
    f32x16 acc2[3];
#pragma unroll
    for (int m = 0; m < 3; ++m) acc2[m] = (f32x16)0.f;
    const int col2 = 32*w + lr;
    const unsigned cswz2 = (unsigned)((col2 & 7) << 4);
    for (int kt2 = 0; kt2 < 8; ++kt2) {
#pragma unroll
        for (int kk = 0; kk < 2; ++kk) {
            int k0 = kt2*32 + kk*16 + lh*8;
            bf16x8 bv = *(const bf16x8*)(smem + ((unsigned)(col2*512 + k0*2) ^ cswz2));
#pragma unroll
            for (int m = 0; m < 3; ++m) {
                bf16x8 av = *(const bf16x8*)(W2p + (32*m + lr)*256 + k0);
                acc2[m] = __builtin_amdgcn_mfma_f32_32x32x16_bf16(av, bv, acc2[m], 0, 0, 0);
            }
        }
    }

    // ---- epilogue 2: stage out-tile f32 [96][128] in LDS ----
    BAR();    // all waves done reading hT
    float* so = (float*)smem;
#pragma unroll
    for (int m = 0; m < 3; ++m)
#pragma unroll
        for (int g = 0; g < 4; ++g) {
            int rbase = 32*m + 8*g + 4*lh;
            if (rbase <= 64) {
#pragma unroll
                for (int r = 0; r < 4; ++r) {
                    int row = rbase + r;
                    if (row < NCH) so[row*128 + col2] = acc2[m][4*g + r] + b2[row];
                }
            }
        }
    BAR();

    // ---- epilogue 3: per-position pack + coalesced dense writes ----
    {
        const int p   = tid & 127;
        const int phw = hw0 + p;
        const int b9  = bidx * NA;
        if (tid < 128) {
            // waves 0-1: conf (f32 planar) + off (bf16x4 interleaved, 8B/anchor)
#pragma unroll
            for (int a = 0; a < 9; ++a) {
                float v0 = so[(5*a+0)*128 + p];
                float v1 = so[(5*a+1)*128 + p];
                float v2 = so[(5*a+2)*128 + p];
                float v3 = so[(5*a+3)*128 + p];
                float v4 = so[(5*a+4)*128 + p];
                int abase = ((b9 + a) << 12) + phw;
                conf_d[abase] = sigf(v0);
                bf16x4 o;
                o[0] = (__bf16)(sigf(v1) - 0.5f);
                o[1] = (__bf16)(sigf(v2) - 0.5f);
                o[2] = (__bf16)v3;
                o[3] = (__bf16)v4;
                *(bf16x4*)(off_w + ((size_t)abase << 2)) = o;
            }
        } else {
            // waves 2-3: cls, full 64B sector per position (pad rows 20..31 = 0)
            unsigned short* dst = cls_w + ((size_t)((bidx << 12) + phw) << 5);
#pragma unroll
            for (int q = 0; q < 4; ++q) {
                bf16x8 v;
#pragma unroll
                for (int r = 0; r < 8; ++r) {
                    int c = q*8 + r;
                    v[r] = (c < 20) ? (__bf16)so[(45 + c)*128 + p] : (__bf16)0.f;
                }
                *(bf16x8*)(dst + q*8) = v;
            }
        }
    }
}

// roles by block range (uniform): [0,2M) conf pos|neg ; [2M,3M) off ; [3M,4M) cls
__global__ void gather_all(const int* __restrict__ pos, const int* __restrict__ neg,
                           const float* __restrict__ conf_d,
                           const unsigned short* __restrict__ off_w,
                           const unsigned short* __restrict__ cls_w,
                           float* __restrict__ out) {
    int t = blockIdx.x * 256 + threadIdx.x;
    if (t < 2*M_) {
        int idx = (t < M_) ? pos[t] : neg[t - M_];
        out[t] = conf_d[idx];
    } else if (t < 3*M_) {
        int i = t - 2*M_;
        int p = pos[i];
        bf16x4 o = *(const bf16x4*)(off_w + ((size_t)p << 2));
        f32x4 f;
        f[0] = (float)o[0]; f[1] = (float)o[1];
        f[2] = (float)o[2]; f[3] = (float)o[3];
        *(f32x4*)(out + 2*(size_t)M_ + 4*(size_t)i) = f;
    } else {
        int i = t - 3*M_;
        int p = pos[i];
        int hw = p & 4095;
        int b  = (p >> 12) / 9;
        const unsigned short* src = cls_w + ((size_t)((b << 12) + hw) << 5);
        float* dst = out + 6*(size_t)M_ + 20*(size_t)i;
        bf16x8 v0 = *(const bf16x8*)(src);
        bf16x8 v1 = *(const bf16x8*)(src + 8);
        bf16x4 v2 = *(const bf16x4*)(src + 16);
        f32x4 f;
        f[0] = (float)v0[0]; f[1] = (float)v0[1]; f[2] = (float)v0[2]; f[3] = (float)v0[3];
        *(f32x4*)(dst) = f;
        f[0] = (float)v0[4]; f[1] = (float)v0[5]; f[2] = (float)v0[6]; f[3] = (float)v0[7];
        *(f32x4*)(dst + 4) = f;
        f[0] = (float)v1[0]; f[1] = (float)v1[1]; f[2] = (float)v1[2]; f[3] = (float)v1[3];
        *(f32x4*)(dst + 8) = f;
        f[0] = (float)v1[4]; f[1] = (float)v1[5]; f[2] = (float)v1[6]; f[3] = (float)v1[7];
        *(f32x4*)(dst + 12) = f;
        f[0] = (float)v2[0]; f[1] = (float)v2[1]; f[2] = (float)v2[2]; f[3] = (float)v2[3];
        *(f32x4*)(dst + 16) = f;
    }
}

extern "C" void kernel_launch(void* const* d_in, const int* in_sizes, int n_in,
                              void* d_out, int out_size, void* d_ws, size_t ws_size,
                              hipStream_t stream) {
    const float* feat = (const float*)d_in[0];
    const float* W1   = (const float*)d_in[1];
    const float* b1   = (const float*)d_in[2];
    const float* W2   = (const float*)d_in[3];
    const float* b2   = (const float*)d_in[4];
    const int*   pos  = (const int*)d_in[5];
    const int*   neg  = (const int*)d_in[6];
    float* out = (float*)d_out;

    char* ws = (char*)d_ws;
    unsigned short* W1bt = (unsigned short*)ws;
    unsigned short* W2p  = (unsigned short*)(ws + 262144);
    float*          conf_d = (float*)(ws + 311296);
    unsigned short* off_w  = (unsigned short*)(ws + 5029888);
    unsigned short* cls_w  = (unsigned short*)(ws + 14467072);

    prep_weights<<<608, 256, 0, stream>>>(W1, W2, W1bt, W2p);
    // MEASUREMENT: launch fused_mlp TWICE (idempotent). dur_us - 92.2 = mlp time.
    fused_mlp<<<1024, 256, 0, stream>>>(feat, b1, b2, W1bt, W2p, conf_d, off_w, cls_w);
    fused_mlp<<<1024, 256, 0, stream>>>(feat, b1, b2, W1bt, W2p, conf_d, off_w, cls_w);
    gather_all<<<1024, 256, 0, stream>>>(pos, neg, conf_d, off_w, cls_w, out);
}

// Round 11
// 121.750 us; speedup vs baseline: 1.3520x; 1.3520x over previous
//
#include <hip/hip_runtime.h>
#include <hip/hip_bf16.h>

typedef __attribute__((ext_vector_type(8)))  __bf16 bf16x8;
typedef __attribute__((ext_vector_type(4)))  __bf16 bf16x4;
typedef __attribute__((ext_vector_type(16))) float  f32x16;
typedef __attribute__((ext_vector_type(4)))  float  f32x4;

#define B_    32
#define CIN   512
#define HID   256
#define HW    4096
#define NA    9
#define NCH   65      // 5*9 + 20
#define NPADC 128     // padded GEMM2 rows (2x2 wave split; rows >=65 zero)
#define BN    256     // spatial tile per block (1KB contiguous per k-plane read)
#define M_    65536
#define NTOT  (B_*NA*HW)   // 1179648

// LDS-only barrier: drains DS ops, leaves global prefetches (vmcnt) in flight.
#define BAR() do {                                          \
    asm volatile("s_waitcnt lgkmcnt(0)" ::: "memory");      \
    __builtin_amdgcn_s_barrier();                           \
    __builtin_amdgcn_sched_barrier(0);                      \
} while (0)

// Workspace layout (bytes):
//   [0)         W1bt  bf16 [16][256][32]     262144  (K-tiled; L2-resident)
//   [262144)    W2p   bf16 [128][256]         65536  (rows >=65 zero)
//   [327680)    conf_d f32  [NTOT]          4718592
//   [5046272)   off_w  bf16 [NTOT][4]       9437184  (interleaved: 8B = 1-line gather)
//   [14483456)  cls_w  bf16 [B*HW][32]      8388608  (64B-aligned full-sector rows)

static __device__ __forceinline__ float sigf(float v) {
    return 1.f / (1.f + __expf(-v));
}

__global__ void prep_weights(const float* __restrict__ W1, const float* __restrict__ W2,
                             unsigned short* __restrict__ W1bt, unsigned short* __restrict__ W2p) {
    int i = blockIdx.x * 256 + threadIdx.x;
    if (i < 16*256*32) {
        int kt = i >> 13, o = (i >> 5) & 255, kk = i & 31;
        __bf16 h = (__bf16)W1[o*CIN + kt*32 + kk];
        W1bt[i] = __builtin_bit_cast(unsigned short, h);
    } else {
        int j = i - 16*256*32;
        if (j < NPADC*HID) {
            int o = j >> 8, c = j & 255;
            float v = (o < NCH) ? W2[o*HID + c] : 0.f;
            __bf16 h = (__bf16)v;
            W2p[j] = __builtin_bit_cast(unsigned short, h);
        }
    }
}

// 8 waves (512 thr). Block tile 256(M=hid) x 256(N=spatial); wave (mg,ng):
// wave tile 64 M x 128 N, acc[2][4]=128 VGPR. Per k-plane the block reads
// 1KB CONTIGUOUS (vs 512B at BN=128) -> better DRAM page locality.
// A direct from L2-resident W1bt, issued BEFORE B in the FIFO. B dbuf in LDS,
// distance 2; ONE lgkm-only barrier/iter. Tail = two 128-col passes reusing
// the 64KB LDS (hT + out-stage), GEMM2 2x2 wave split (NPADC=128).
__launch_bounds__(512, 2)
__global__ void fused_mlp(const float* __restrict__ feat,
                          const float* __restrict__ b1,
                          const float* __restrict__ b2,
                          const unsigned short* __restrict__ W1bt,
                          const unsigned short* __restrict__ W2p,
                          float* __restrict__ conf_d,
                          unsigned short* __restrict__ off_w,
                          unsigned short* __restrict__ cls_w) {
    // K-loop: Bs0 [0,20480) bf16[256][40]; Bs1 [20480,40960)
    // Tail pass p: hT 64KB bf16 (c*512 + k*2) ^ ((c&7)<<4), c = pass-local col;
    //              then so f32 [<=96][128] (48KB)
    __shared__ __align__(16) unsigned char smem[65536];

    const int tid  = threadIdx.x;
    const int w    = tid >> 6;         // 0..7
    const int lane = tid & 63;
    const int lr   = lane & 31;
    const int lh   = lane >> 5;
    const int mg   = w >> 1;           // A-row group (64 rows each)
    const int ng   = w & 1;            // column half (128 cols each)
    const int bidx = blockIdx.x >> 4;
    const int hw0  = (blockIdx.x & 15) * BN;

    const float* fb = feat + (size_t)bidx * CIN * HW + hw0;

    const int sB  = tid & 255;        // B staging: spatial column
    const int kgB = tid >> 8;         // k-group 0/1 (handles kgB and kgB+2)

    f32x16 acc[2][4];
#pragma unroll
    for (int m = 0; m < 2; ++m)
#pragma unroll
        for (int n = 0; n < 4; ++n) acc[m][n] = (f32x16)0.f;

    float  pb[2][16];    // two in-flight feature tiles
    bf16x8 aw[2][4];     // two in-flight A-fragment sets: [set][kk*2+m]

    auto issueB = [&](int kt, int s) {
#pragma unroll
        for (int q = 0; q < 2; ++q) {
            const float* src = fb + (size_t)(kt*32 + (kgB + 2*q)*8) * HW + sB;
#pragma unroll
            for (int j = 0; j < 8; ++j) pb[s][q*8 + j] = src[(size_t)j * HW];
        }
    };
    auto issueA = [&](int kt, int s) {
#pragma unroll
        for (int kk = 0; kk < 2; ++kk)
#pragma unroll
            for (int m = 0; m < 2; ++m)
                aw[s][kk*2 + m] = *(const bf16x8*)(W1bt + kt*8192 + (64*mg + 32*m + lr)*32 + kk*16 + lh*8);
    };
    auto storeB = [&](int s) {
        unsigned short* Bst = (unsigned short*)(smem + s*20480);
#pragma unroll
        for (int q = 0; q < 2; ++q) {
            bf16x8 v8;
#pragma unroll
            for (int j = 0; j < 8; ++j) v8[j] = (__bf16)pb[s][q*8 + j];
            *(bf16x8*)(Bst + sB*40 + (kgB + 2*q)*8) = v8;   // row=spatial, col=k
        }
    };

    // prologue: A(0), B(0), B(1) issued (A first in FIFO); store B(0)
    issueA(0, 0); issueB(0, 0); issueB(1, 1);
    storeB(0);               // drains A(0)+B(0); B(1) stays in flight
    BAR();

#pragma unroll
    for (int kt = 0; kt < 16; ++kt) {
        const int cur = kt & 1, nxt = cur ^ 1;
        if (kt + 1 < 16) issueA(kt + 1, nxt);     // L2 A-frags first in queue
        if (kt + 2 < 16) issueB(kt + 2, cur);     // HBM prefetch behind them
        const unsigned short* Bst = (const unsigned short*)(smem + cur*20480);
#pragma unroll
        for (int kk = 0; kk < 2; ++kk) {
            bf16x8 a0 = aw[cur][kk*2 + 0];
            bf16x8 a1 = aw[cur][kk*2 + 1];
#pragma unroll
            for (int n = 0; n < 4; ++n) {
                bf16x8 bv = *(const bf16x8*)(Bst + (128*ng + 32*n + lr)*40 + kk*16 + lh*8);
                acc[0][n] = __builtin_amdgcn_mfma_f32_32x32x16_bf16(a0, bv, acc[0][n], 0, 0, 0);
                acc[1][n] = __builtin_amdgcn_mfma_f32_32x32x16_bf16(a1, bv, acc[1][n], 0, 0, 0);
            }
        }
        if (kt + 1 < 16) storeB(nxt);             // waits only B(kt+1); B(kt+2) in flight
        BAR();                                    // lgkm only
    }

    // ============ tail: two 128-col passes reusing the 64KB LDS ============
#pragma unroll
    for (int p = 0; p < 2; ++p) {
        // ---- epi1: waves with ng==p write hT (leaky(h+b1), bf16, swizzled) ----
        if (ng == p) {
#pragma unroll
            for (int m = 0; m < 2; ++m)
#pragma unroll
                for (int n = 0; n < 4; ++n) {
                    int c = 32*n + lr;                       // pass-local col
                    unsigned cswz = (unsigned)((c & 7) << 4);
#pragma unroll
                    for (int g = 0; g < 4; ++g) {
                        int rbase = 64*mg + 32*m + 8*g + 4*lh;
                        f32x4 b1v = *(const f32x4*)(b1 + rbase);
                        bf16x4 pk;
#pragma unroll
                        for (int r = 0; r < 4; ++r) {
                            float v = acc[m][n][4*g + r] + b1v[r];
                            v = v > 0.f ? v : 0.01f * v;
                            pk[r] = (__bf16)v;
                        }
                        *(bf16x4*)(smem + ((unsigned)(c*512 + rbase*2) ^ cswz)) = pk;
                    }
                }
        }
        BAR();

        // ---- GEMM2: out[128][128] = W2p[128][256] @ hT; 4 col x 2 row waves ----
        f32x16 acc2[2];
#pragma unroll
        for (int m = 0; m < 2; ++m) acc2[m] = (f32x16)0.f;
        const int colh = w & 3, rowh = w >> 2;
        const int col2 = 32*colh + lr;
        const unsigned cswz2 = (unsigned)((col2 & 7) << 4);
#pragma unroll
        for (int kt2 = 0; kt2 < 8; ++kt2) {
#pragma unroll
            for (int kk = 0; kk < 2; ++kk) {
                int k0 = kt2*32 + kk*16 + lh*8;
                bf16x8 bv2 = *(const bf16x8*)(smem + ((unsigned)(col2*512 + k0*2) ^ cswz2));
#pragma unroll
                for (int m = 0; m < 2; ++m) {
                    bf16x8 av = *(const bf16x8*)(W2p + (64*rowh + 32*m + lr)*256 + k0);
                    acc2[m] = __builtin_amdgcn_mfma_f32_32x32x16_bf16(av, bv2, acc2[m], 0, 0, 0);
                }
            }
        }
        BAR();   // hT reads done before out-stage overwrite

        // ---- epi2: stage out f32 [rows<65][128] ----
        float* so = (float*)smem;
#pragma unroll
        for (int m = 0; m < 2; ++m)
#pragma unroll
            for (int g = 0; g < 4; ++g) {
                int rbase = 64*rowh + 32*m + 8*g + 4*lh;
                if (rbase <= 64) {
#pragma unroll
                    for (int r = 0; r < 4; ++r) {
                        int row = rbase + r;
                        if (row < NCH) so[row*128 + col2] = acc2[m][4*g + r] + b2[row];
                    }
                }
            }
        BAR();

        // ---- epi3: per-position pack + coalesced dense writes ----
        {
            const int pp  = tid & 127;
            const int phw = hw0 + 128*p + pp;
            const int b9  = bidx * NA;
            if (tid < 128) {
                // conf (f32 planar) + off (bf16x4 interleaved, 8B/anchor)
#pragma unroll
                for (int a = 0; a < 9; ++a) {
                    float v0 = so[(5*a+0)*128 + pp];
                    float v1 = so[(5*a+1)*128 + pp];
                    float v2 = so[(5*a+2)*128 + pp];
                    float v3 = so[(5*a+3)*128 + pp];
                    float v4 = so[(5*a+4)*128 + pp];
                    int abase = ((b9 + a) << 12) + phw;
                    conf_d[abase] = sigf(v0);
                    bf16x4 o;
                    o[0] = (__bf16)(sigf(v1) - 0.5f);
                    o[1] = (__bf16)(sigf(v2) - 0.5f);
                    o[2] = (__bf16)v3;
                    o[3] = (__bf16)v4;
                    *(bf16x4*)(off_w + ((size_t)abase << 2)) = o;
                }
            } else if (tid < 256) {
                // cls, full 64B sector per position (pad rows 20..31 = 0)
                unsigned short* dst = cls_w + ((size_t)((bidx << 12) + phw) << 5);
#pragma unroll
                for (int q = 0; q < 4; ++q) {
                    bf16x8 v;
#pragma unroll
                    for (int r = 0; r < 8; ++r) {
                        int c = q*8 + r;
                        v[r] = (c < 20) ? (__bf16)so[(45 + c)*128 + pp] : (__bf16)0.f;
                    }
                    *(bf16x8*)(dst + q*8) = v;
                }
            }
        }
        BAR();   // epi3 so-reads done before next pass's epi1 overwrites LDS
    }
}

// roles by block range (uniform): [0,2M) conf pos|neg ; [2M,3M) off ; [3M,4M) cls
__global__ void gather_all(const int* __restrict__ pos, const int* __restrict__ neg,
                           const float* __restrict__ conf_d,
                           const unsigned short* __restrict__ off_w,
                           const unsigned short* __restrict__ cls_w,
                           float* __restrict__ out) {
    int t = blockIdx.x * 256 + threadIdx.x;
    if (t < 2*M_) {
        int idx = (t < M_) ? pos[t] : neg[t - M_];
        out[t] = conf_d[idx];
    } else if (t < 3*M_) {
        int i = t - 2*M_;
        int p = pos[i];
        bf16x4 o = *(const bf16x4*)(off_w + ((size_t)p << 2));
        f32x4 f;
        f[0] = (float)o[0]; f[1] = (float)o[1];
        f[2] = (float)o[2]; f[3] = (float)o[3];
        *(f32x4*)(out + 2*(size_t)M_ + 4*(size_t)i) = f;
    } else {
        int i = t - 3*M_;
        int p = pos[i];
        int hw = p & 4095;
        int b  = (p >> 12) / 9;
        const unsigned short* src = cls_w + ((size_t)((b << 12) + hw) << 5);
        float* dst = out + 6*(size_t)M_ + 20*(size_t)i;
        bf16x8 v0 = *(const bf16x8*)(src);
        bf16x8 v1 = *(const bf16x8*)(src + 8);
        bf16x4 v2 = *(const bf16x4*)(src + 16);
        f32x4 f;
        f[0] = (float)v0[0]; f[1] = (float)v0[1]; f[2] = (float)v0[2]; f[3] = (float)v0[3];
        *(f32x4*)(dst) = f;
        f[0] = (float)v0[4]; f[1] = (float)v0[5]; f[2] = (float)v0[6]; f[3] = (float)v0[7];
        *(f32x4*)(dst + 4) = f;
        f[0] = (float)v1[0]; f[1] = (float)v1[1]; f[2] = (float)v1[2]; f[3] = (float)v1[3];
        *(f32x4*)(dst + 8) = f;
        f[0] = (float)v1[4]; f[1] = (float)v1[5]; f[2] = (float)v1[6]; f[3] = (float)v1[7];
        *(f32x4*)(dst + 12) = f;
        f[0] = (float)v2[0]; f[1] = (float)v2[1]; f[2] = (float)v2[2]; f[3] = (float)v2[3];
        *(f32x4*)(dst + 16) = f;
    }
}

extern "C" void kernel_launch(void* const* d_in, const int* in_sizes, int n_in,
                              void* d_out, int out_size, void* d_ws, size_t ws_size,
                              hipStream_t stream) {
    const float* feat = (const float*)d_in[0];
    const float* W1   = (const float*)d_in[1];
    const float* b1   = (const float*)d_in[2];
    const float* W2   = (const float*)d_in[3];
    const float* b2   = (const float*)d_in[4];
    const int*   pos  = (const int*)d_in[5];
    const int*   neg  = (const int*)d_in[6];
    float* out = (float*)d_out;

    char* ws = (char*)d_ws;
    unsigned short* W1bt = (unsigned short*)ws;
    unsigned short* W2p  = (unsigned short*)(ws + 262144);
    float*          conf_d = (float*)(ws + 327680);
    unsigned short* off_w  = (unsigned short*)(ws + 5046272);
    unsigned short* cls_w  = (unsigned short*)(ws + 14483456);

    prep_weights<<<640, 256, 0, stream>>>(W1, W2, W1bt, W2p);
    fused_mlp<<<512, 512, 0, stream>>>(feat, b1, b2, W1bt, W2p, conf_d, off_w, cls_w);
    gather_all<<<1024, 256, 0, stream>>>(pos, neg, conf_d, off_w, cls_w, out);
}

// Round 12
// 91.274 us; speedup vs baseline: 1.8034x; 1.3339x over previous
//
#include <hip/hip_runtime.h>
#include <hip/hip_bf16.h>

typedef __attribute__((ext_vector_type(8)))  __bf16 bf16x8;
typedef __attribute__((ext_vector_type(4)))  __bf16 bf16x4;
typedef __attribute__((ext_vector_type(16))) float  f32x16;
typedef __attribute__((ext_vector_type(4)))  float  f32x4;

#define B_    32
#define CIN   512
#define HID   256
#define HW    4096
#define NA    9
#define NCH   65      // 5*9 + 20
#define NPADC 96
#define BN    128     // spatial tile per block
#define M_    65536
#define NTOT  (B_*NA*HW)   // 1179648

// LDS-only barrier: drains DS ops, leaves global prefetches (vmcnt) in flight.
#define BAR() do {                                          \
    asm volatile("s_waitcnt lgkmcnt(0)" ::: "memory");      \
    __builtin_amdgcn_s_barrier();                           \
    __builtin_amdgcn_sched_barrier(0);                      \
} while (0)

// Workspace layout (bytes):
//   [0)         W1bt  bf16 [16][256][32]     262144  (K-tiled; L2-resident)
//   [262144)    W2p   bf16 [96][256]          49152  (rows >=65 zero)
//   [311296)    conf_d f32  [NTOT]          4718592
//   [5029888)   off_w  bf16 [NTOT][4]       9437184  (interleaved: 8B = 1-line gather)
//   [14467072)  cls_w  bf16 [B*HW][32]      8388608  (64B-aligned full-sector rows)

static __device__ __forceinline__ float sigf(float v) {
    return 1.f / (1.f + __expf(-v));
}

__global__ void prep_weights(const float* __restrict__ W1, const float* __restrict__ W2,
                             unsigned short* __restrict__ W1bt, unsigned short* __restrict__ W2p) {
    int i = blockIdx.x * 256 + threadIdx.x;
    if (i < 16*256*32) {
        int kt = i >> 13, o = (i >> 5) & 255, kk = i & 31;
        __bf16 h = (__bf16)W1[o*CIN + kt*32 + kk];
        W1bt[i] = __builtin_bit_cast(unsigned short, h);
    } else {
        int j = i - 16*256*32;
        if (j < NPADC*HID) {
            int o = j >> 8, c = j & 255;
            float v = (o < NCH) ? W2[o*HID + c] : 0.f;
            __bf16 h = (__bf16)v;
            W2p[j] = __builtin_bit_cast(unsigned short, h);
        }
    }
}

// 4 waves. GEMM1: h[256][128] = W1[256x512] @ F[512x128]; wave tile 64(M)x128(N).
// A direct from L2-resident W1bt, issued BEFORE B in the FIFO (A-wait never
// drains the HBM B-prefetch). B double-buffered in LDS, issue distance 2;
// ONE lgkm-only barrier/iter. (R5 champion structure; GEMM2 kt2 loop unrolled.)
__launch_bounds__(256, 2)
__global__ void fused_mlp(const float* __restrict__ feat,
                          const float* __restrict__ b1,
                          const float* __restrict__ b2,
                          const unsigned short* __restrict__ W1bt,
                          const unsigned short* __restrict__ W2p,
                          float* __restrict__ conf_d,
                          unsigned short* __restrict__ off_w,
                          unsigned short* __restrict__ cls_w) {
    // union: [0,10240) Bs0 bf16[128][40]; [10240,20480) Bs1;
    //        after GEMM1: 64KB hT bf16 (col*512 + k*2) ^ ((col&7)<<4);
    //        after GEMM2: f32 out-stage [96][128] (48KB)
    __shared__ __align__(16) unsigned char smem[65536];

    const int tid  = threadIdx.x;
    const int w    = tid >> 6;
    const int lane = tid & 63;
    const int lr   = lane & 31;
    const int lh   = lane >> 5;
    const int bidx = blockIdx.x >> 5;
    const int hw0  = (blockIdx.x & 31) * BN;

    const float* fb = feat + (size_t)bidx * CIN * HW + hw0;

    const int sB  = tid & 127;        // B staging: spatial column
    const int kgB = tid >> 7;         // k-group 0/1 (handles kgB and kgB+2)

    f32x16 acc[2][4];
#pragma unroll
    for (int m = 0; m < 2; ++m)
#pragma unroll
        for (int n = 0; n < 4; ++n) acc[m][n] = (f32x16)0.f;

    float  pb[2][16];    // two in-flight feature tiles
    bf16x8 aw[2][4];     // two in-flight A-fragment sets: [set][kk*2+m]

    auto issueB = [&](int kt, int s) {
#pragma unroll
        for (int q = 0; q < 2; ++q) {
            const float* src = fb + (size_t)(kt*32 + (kgB + 2*q)*8) * HW + sB;
#pragma unroll
            for (int j = 0; j < 8; ++j) pb[s][q*8 + j] = src[(size_t)j * HW];
        }
    };
    auto issueA = [&](int kt, int s) {
#pragma unroll
        for (int kk = 0; kk < 2; ++kk)
#pragma unroll
            for (int m = 0; m < 2; ++m)
                aw[s][kk*2 + m] = *(const bf16x8*)(W1bt + kt*8192 + (64*w + 32*m + lr)*32 + kk*16 + lh*8);
    };
    auto storeB = [&](int s) {
        unsigned short* Bst = (unsigned short*)(smem + s*10240);
#pragma unroll
        for (int q = 0; q < 2; ++q) {
            bf16x8 v8;
#pragma unroll
            for (int j = 0; j < 8; ++j) v8[j] = (__bf16)pb[s][q*8 + j];
            *(bf16x8*)(Bst + sB*40 + (kgB + 2*q)*8) = v8;   // row=spatial, col=k
        }
    };

    // prologue: A(0), B(0), B(1) issued (A first in FIFO); store B(0)
    issueA(0, 0); issueB(0, 0); issueB(1, 1);
    storeB(0);               // waits vmcnt(16): drains A(0)+B(0), leaves B(1) in flight
    BAR();

#pragma unroll
    for (int kt = 0; kt < 16; ++kt) {
        const int cur = kt & 1, nxt = cur ^ 1;
        if (kt + 1 < 16) issueA(kt + 1, nxt);     // L2 A-frags first in queue
        if (kt + 2 < 16) issueB(kt + 2, cur);     // HBM prefetch behind them
        const unsigned short* Bst = (const unsigned short*)(smem + cur*10240);
#pragma unroll
        for (int kk = 0; kk < 2; ++kk) {
            bf16x8 a0 = aw[cur][kk*2 + 0];
            bf16x8 a1 = aw[cur][kk*2 + 1];
#pragma unroll
            for (int n = 0; n < 4; ++n) {
                bf16x8 bv = *(const bf16x8*)(Bst + (32*n + lr)*40 + kk*16 + lh*8);
                acc[0][n] = __builtin_amdgcn_mfma_f32_32x32x16_bf16(a0, bv, acc[0][n], 0, 0, 0);
                acc[1][n] = __builtin_amdgcn_mfma_f32_32x32x16_bf16(a1, bv, acc[1][n], 0, 0, 0);
            }
        }
        if (kt + 1 < 16) storeB(nxt);             // waits vmcnt(20): B(kt+1) only
        BAR();                                    // lgkm only; 20 loads stay in flight
    }

    // ---- epilogue 1: h = leaky(h + b1) -> hT in LDS (bf16, swizzled) ----
#pragma unroll
    for (int m = 0; m < 2; ++m)
#pragma unroll
        for (int n = 0; n < 4; ++n) {
            int col = 32*n + lr;
            unsigned cswz = (unsigned)((col & 7) << 4);
#pragma unroll
            for (int g = 0; g < 4; ++g) {
                int rbase = 64*w + 32*m + 8*g + 4*lh;        // h row (HID channel)
                f32x4 b1v = *(const f32x4*)(b1 + rbase);
                bf16x4 pk;
#pragma unroll
                for (int r = 0; r < 4; ++r) {
                    float v = acc[m][n][4*g + r] + b1v[r];
                    v = v > 0.f ? v : 0.01f * v;
                    pk[r] = (__bf16)v;
                }
                unsigned addr = (unsigned)(col*512 + rbase*2) ^ cswz;
                *(bf16x4*)(smem + addr) = pk;
            }
        }
    BAR();

    // ---- GEMM2: out[96][128] = W2p[96][256] @ h[256][128]; wave owns 32 cols ----
    f32x16 acc2[3];
#pragma unroll
    for (int m = 0; m < 3; ++m) acc2[m] = (f32x16)0.f;
    const int col2 = 32*w + lr;
    const unsigned cswz2 = (unsigned)((col2 & 7) << 4);
#pragma unroll
    for (int kt2 = 0; kt2 < 8; ++kt2) {
#pragma unroll
        for (int kk = 0; kk < 2; ++kk) {
            int k0 = kt2*32 + kk*16 + lh*8;
            bf16x8 bv = *(const bf16x8*)(smem + ((unsigned)(col2*512 + k0*2) ^ cswz2));
#pragma unroll
            for (int m = 0; m < 3; ++m) {
                bf16x8 av = *(const bf16x8*)(W2p + (32*m + lr)*256 + k0);
                acc2[m] = __builtin_amdgcn_mfma_f32_32x32x16_bf16(av, bv, acc2[m], 0, 0, 0);
            }
        }
    }

    // ---- epilogue 2: stage out-tile f32 [96][128] in LDS ----
    BAR();    // all waves done reading hT
    float* so = (float*)smem;
#pragma unroll
    for (int m = 0; m < 3; ++m)
#pragma unroll
        for (int g = 0; g < 4; ++g) {
            int rbase = 32*m + 8*g + 4*lh;
            if (rbase <= 64) {
#pragma unroll
                for (int r = 0; r < 4; ++r) {
                    int row = rbase + r;
                    if (row < NCH) so[row*128 + col2] = acc2[m][4*g + r] + b2[row];
                }
            }
        }
    BAR();

    // ---- epilogue 3: per-position pack + coalesced dense writes ----
    {
        const int p   = tid & 127;
        const int phw = hw0 + p;
        const int b9  = bidx * NA;
        if (tid < 128) {
            // waves 0-1: conf (f32 planar) + off (bf16x4 interleaved, 8B/anchor)
#pragma unroll
            for (int a = 0; a < 9; ++a) {
                float v0 = so[(5*a+0)*128 + p];
                float v1 = so[(5*a+1)*128 + p];
                float v2 = so[(5*a+2)*128 + p];
                float v3 = so[(5*a+3)*128 + p];
                float v4 = so[(5*a+4)*128 + p];
                int abase = ((b9 + a) << 12) + phw;
                conf_d[abase] = sigf(v0);
                bf16x4 o;
                o[0] = (__bf16)(sigf(v1) - 0.5f);
                o[1] = (__bf16)(sigf(v2) - 0.5f);
                o[2] = (__bf16)v3;
                o[3] = (__bf16)v4;
                *(bf16x4*)(off_w + ((size_t)abase << 2)) = o;
            }
        } else {
            // waves 2-3: cls, full 64B sector per position (pad rows 20..31 = 0)
            unsigned short* dst = cls_w + ((size_t)((bidx << 12) + phw) << 5);
#pragma unroll
            for (int q = 0; q < 4; ++q) {
                bf16x8 v;
#pragma unroll
                for (int r = 0; r < 8; ++r) {
                    int c = q*8 + r;
                    v[r] = (c < 20) ? (__bf16)so[(45 + c)*128 + p] : (__bf16)0.f;
                }
                *(bf16x8*)(dst + q*8) = v;
            }
        }
    }
}

// roles by block range (uniform): [0,2M) conf pos|neg ; [2M,3M) off ; [3M,4M) cls
__global__ void gather_all(const int* __restrict__ pos, const int* __restrict__ neg,
                           const float* __restrict__ conf_d,
                           const unsigned short* __restrict__ off_w,
                           const unsigned short* __restrict__ cls_w,
                           float* __restrict__ out) {
    int t = blockIdx.x * 256 + threadIdx.x;
    if (t < 2*M_) {
        int idx = (t < M_) ? pos[t] : neg[t - M_];
        out[t] = conf_d[idx];
    } else if (t < 3*M_) {
        int i = t - 2*M_;
        int p = pos[i];
        bf16x4 o = *(const bf16x4*)(off_w + ((size_t)p << 2));
        f32x4 f;
        f[0] = (float)o[0]; f[1] = (float)o[1];
        f[2] = (float)o[2]; f[3] = (float)o[3];
        *(f32x4*)(out + 2*(size_t)M_ + 4*(size_t)i) = f;
    } else {
        int i = t - 3*M_;
        int p = pos[i];
        int hw = p & 4095;
        int b  = (p >> 12) / 9;
        const unsigned short* src = cls_w + ((size_t)((b << 12) + hw) << 5);
        float* dst = out + 6*(size_t)M_ + 20*(size_t)i;
        bf16x8 v0 = *(const bf16x8*)(src);
        bf16x8 v1 = *(const bf16x8*)(src + 8);
        bf16x4 v2 = *(const bf16x4*)(src + 16);
        f32x4 f;
        f[0] = (float)v0[0]; f[1] = (float)v0[1]; f[2] = (float)v0[2]; f[3] = (float)v0[3];
        *(f32x4*)(dst) = f;
        f[0] = (float)v0[4]; f[1] = (float)v0[5]; f[2] = (float)v0[6]; f[3] = (float)v0[7];
        *(f32x4*)(dst + 4) = f;
        f[0] = (float)v1[0]; f[1] = (float)v1[1]; f[2] = (float)v1[2]; f[3] = (float)v1[3];
        *(f32x4*)(dst + 8) = f;
        f[0] = (float)v1[4]; f[1] = (float)v1[5]; f[2] = (float)v1[6]; f[3] = (float)v1[7];
        *(f32x4*)(dst + 12) = f;
        f[0] = (float)v2[0]; f[1] = (float)v2[1]; f[2] = (float)v2[2]; f[3] = (float)v2[3];
        *(f32x4*)(dst + 16) = f;
    }
}

extern "C" void kernel_launch(void* const* d_in, const int* in_sizes, int n_in,
                              void* d_out, int out_size, void* d_ws, size_t ws_size,
                              hipStream_t stream) {
    const float* feat = (const float*)d_in[0];
    const float* W1   = (const float*)d_in[1];
    const float* b1   = (const float*)d_in[2];
    const float* W2   = (const float*)d_in[3];
    const float* b2   = (const float*)d_in[4];
    const int*   pos  = (const int*)d_in[5];
    const int*   neg  = (const int*)d_in[6];
    float* out = (float*)d_out;

    char* ws = (char*)d_ws;
    unsigned short* W1bt = (unsigned short*)ws;
    unsigned short* W2p  = (unsigned short*)(ws + 262144);
    float*          conf_d = (float*)(ws + 311296);
    unsigned short* off_w  = (unsigned short*)(ws + 5029888);
    unsigned short* cls_w  = (unsigned short*)(ws + 14467072);

    prep_weights<<<608, 256, 0, stream>>>(W1, W2, W1bt, W2p);
    fused_mlp<<<1024, 256, 0, stream>>>(feat, b1, b2, W1bt, W2p, conf_d, off_w, cls_w);
    gather_all<<<1024, 256, 0, stream>>>(pos, neg, conf_d, off_w, cls_w, out);
}

// Round 14
// 91.233 us; speedup vs baseline: 1.8042x; 1.0004x over previous
//
#include <hip/hip_runtime.h>
#include <hip/hip_bf16.h>

typedef __attribute__((ext_vector_type(8)))  __bf16 bf16x8;
typedef __attribute__((ext_vector_type(4)))  __bf16 bf16x4;
typedef __attribute__((ext_vector_type(16))) float  f32x16;
typedef __attribute__((ext_vector_type(4)))  float  f32x4;

#define B_    32
#define CIN   512
#define HID   256
#define HW    4096
#define NA    9
#define NCH   65      // 5*9 + 20
#define NPADC 96
#define BN    128     // spatial tile per block
#define M_    65536
#define NTOT  (B_*NA*HW)   // 1179648

// LDS-only barrier: drains DS ops, leaves global prefetches (vmcnt) in flight.
#define BAR() do {                                          \
    asm volatile("s_waitcnt lgkmcnt(0)" ::: "memory");      \
    __builtin_amdgcn_s_barrier();                           \
    __builtin_amdgcn_sched_barrier(0);                      \
} while (0)

// Workspace layout (bytes):
//   [0)         W1bt  bf16 [16][256][32]     262144  (K-tiled; L2-resident)
//   [262144)    W2p   bf16 [96][256]          49152  (rows >=65 zero)
//   [311296)    conf_d f32  [NTOT]          4718592
//   [5029888)   off_w  bf16 [NTOT][4]       9437184  (interleaved: 8B = 1-line gather)
//   [14467072)  cls_w  bf16 [B*HW][32]      8388608  (64B-aligned full-sector rows)

static __device__ __forceinline__ float sigf(float v) {
    return 1.f / (1.f + __expf(-v));
}

__global__ void prep_weights(const float* __restrict__ W1, const float* __restrict__ W2,
                             unsigned short* __restrict__ W1bt, unsigned short* __restrict__ W2p) {
    int i = blockIdx.x * 256 + threadIdx.x;
    if (i < 16*256*32) {
        int kt = i >> 13, o = (i >> 5) & 255, kk = i & 31;
        __bf16 h = (__bf16)W1[o*CIN + kt*32 + kk];
        W1bt[i] = __builtin_bit_cast(unsigned short, h);
    } else {
        int j = i - 16*256*32;
        if (j < NPADC*HID) {
            int o = j >> 8, c = j & 255;
            float v = (o < NCH) ? W2[o*HID + c] : 0.f;
            __bf16 h = (__bf16)v;
            W2p[j] = __builtin_bit_cast(unsigned short, h);
        }
    }
}

// 4 waves. GEMM1: h[256][128] = W1[256x512] @ F[512x128]; wave tile 64(M)x128(N).
// A direct from L2-resident W1bt, issued BEFORE B in the FIFO (A-wait never
// drains the HBM B-prefetch). B double-buffered in LDS, issue distance 2;
// ONE lgkm-only barrier/iter. (R12 champion: R5 structure + GEMM2 kt2 unroll.)
__launch_bounds__(256, 2)
__global__ void fused_mlp(const float* __restrict__ feat,
                          const float* __restrict__ b1,
                          const float* __restrict__ b2,
                          const unsigned short* __restrict__ W1bt,
                          const unsigned short* __restrict__ W2p,
                          float* __restrict__ conf_d,
                          unsigned short* __restrict__ off_w,
                          unsigned short* __restrict__ cls_w) {
    // union: [0,10240) Bs0 bf16[128][40]; [10240,20480) Bs1;
    //        after GEMM1: 64KB hT bf16 (col*512 + k*2) ^ ((col&7)<<4);
    //        after GEMM2: f32 out-stage [96][128] (48KB)
    __shared__ __align__(16) unsigned char smem[65536];

    const int tid  = threadIdx.x;
    const int w    = tid >> 6;
    const int lane = tid & 63;
    const int lr   = lane & 31;
    const int lh   = lane >> 5;
    const int bidx = blockIdx.x >> 5;
    const int hw0  = (blockIdx.x & 31) * BN;

    const float* fb = feat + (size_t)bidx * CIN * HW + hw0;

    const int sB  = tid & 127;        // B staging: spatial column
    const int kgB = tid >> 7;         // k-group 0/1 (handles kgB and kgB+2)

    f32x16 acc[2][4];
#pragma unroll
    for (int m = 0; m < 2; ++m)
#pragma unroll
        for (int n = 0; n < 4; ++n) acc[m][n] = (f32x16)0.f;

    float  pb[2][16];    // two in-flight feature tiles
    bf16x8 aw[2][4];     // two in-flight A-fragment sets: [set][kk*2+m]

    auto issueB = [&](int kt, int s) {
#pragma unroll
        for (int q = 0; q < 2; ++q) {
            const float* src = fb + (size_t)(kt*32 + (kgB + 2*q)*8) * HW + sB;
#pragma unroll
            for (int j = 0; j < 8; ++j) pb[s][q*8 + j] = src[(size_t)j * HW];
        }
    };
    auto issueA = [&](int kt, int s) {
#pragma unroll
        for (int kk = 0; kk < 2; ++kk)
#pragma unroll
            for (int m = 0; m < 2; ++m)
                aw[s][kk*2 + m] = *(const bf16x8*)(W1bt + kt*8192 + (64*w + 32*m + lr)*32 + kk*16 + lh*8);
    };
    auto storeB = [&](int s) {
        unsigned short* Bst = (unsigned short*)(smem + s*10240);
#pragma unroll
        for (int q = 0; q < 2; ++q) {
            bf16x8 v8;
#pragma unroll
            for (int j = 0; j < 8; ++j) v8[j] = (__bf16)pb[s][q*8 + j];
            *(bf16x8*)(Bst + sB*40 + (kgB + 2*q)*8) = v8;   // row=spatial, col=k
        }
    };

    // prologue: A(0), B(0), B(1) issued (A first in FIFO); store B(0)
    issueA(0, 0); issueB(0, 0); issueB(1, 1);
    storeB(0);               // waits vmcnt(16): drains A(0)+B(0), leaves B(1) in flight
    BAR();

#pragma unroll
    for (int kt = 0; kt < 16; ++kt) {
        const int cur = kt & 1, nxt = cur ^ 1;
        if (kt + 1 < 16) issueA(kt + 1, nxt);     // L2 A-frags first in queue
        if (kt + 2 < 16) issueB(kt + 2, cur);     // HBM prefetch behind them
        const unsigned short* Bst = (const unsigned short*)(smem + cur*10240);
#pragma unroll
        for (int kk = 0; kk < 2; ++kk) {
            bf16x8 a0 = aw[cur][kk*2 + 0];
            bf16x8 a1 = aw[cur][kk*2 + 1];
#pragma unroll
            for (int n = 0; n < 4; ++n) {
                bf16x8 bv = *(const bf16x8*)(Bst + (32*n + lr)*40 + kk*16 + lh*8);
                acc[0][n] = __builtin_amdgcn_mfma_f32_32x32x16_bf16(a0, bv, acc[0][n], 0, 0, 0);
                acc[1][n] = __builtin_amdgcn_mfma_f32_32x32x16_bf16(a1, bv, acc[1][n], 0, 0, 0);
            }
        }
        if (kt + 1 < 16) storeB(nxt);             // waits vmcnt(20): B(kt+1) only
        BAR();                                    // lgkm only; 20 loads stay in flight
    }

    // ---- epilogue 1: h = leaky(h + b1) -> hT in LDS (bf16, swizzled) ----
#pragma unroll
    for (int m = 0; m < 2; ++m)
#pragma unroll
        for (int n = 0; n < 4; ++n) {
            int col = 32*n + lr;
            unsigned cswz = (unsigned)((col & 7) << 4);
#pragma unroll
            for (int g = 0; g < 4; ++g) {
                int rbase = 64*w + 32*m + 8*g + 4*lh;        // h row (HID channel)
                f32x4 b1v = *(const f32x4*)(b1 + rbase);
                bf16x4 pk;
#pragma unroll
                for (int r = 0; r < 4; ++r) {
                    float v = acc[m][n][4*g + r] + b1v[r];
                    v = v > 0.f ? v : 0.01f * v;
                    pk[r] = (__bf16)v;
                }
                unsigned addr = (unsigned)(col*512 + rbase*2) ^ cswz;
                *(bf16x4*)(smem + addr) = pk;
            }
        }
    BAR();

    // ---- GEMM2: out[96][128] = W2p[96][256] @ h[256][128]; wave owns 32 cols ----
    f32x16 acc2[3];
#pragma unroll
    for (int m = 0; m < 3; ++m) acc2[m] = (f32x16)0.f;
    const int col2 = 32*w + lr;
    const unsigned cswz2 = (unsigned)((col2 & 7) << 4);
#pragma unroll
    for (int kt2 = 0; kt2 < 8; ++kt2) {
#pragma unroll
        for (int kk = 0; kk < 2; ++kk) {
            int k0 = kt2*32 + kk*16 + lh*8;
            bf16x8 bv = *(const bf16x8*)(smem + ((unsigned)(col2*512 + k0*2) ^ cswz2));
#pragma unroll
            for (int m = 0; m < 3; ++m) {
                bf16x8 av = *(const bf16x8*)(W2p + (32*m + lr)*256 + k0);
                acc2[m] = __builtin_amdgcn_mfma_f32_32x32x16_bf16(av, bv, acc2[m], 0, 0, 0);
            }
        }
    }

    // ---- epilogue 2: stage out-tile f32 [96][128] in LDS ----
    BAR();    // all waves done reading hT
    float* so = (float*)smem;
#pragma unroll
    for (int m = 0; m < 3; ++m)
#pragma unroll
        for (int g = 0; g < 4; ++g) {
            int rbase = 32*m + 8*g + 4*lh;
            if (rbase <= 64) {
#pragma unroll
                for (int r = 0; r < 4; ++r) {
                    int row = rbase + r;
                    if (row < NCH) so[row*128 + col2] = acc2[m][4*g + r] + b2[row];
                }
            }
        }
    BAR();

    // ---- epilogue 3: per-position pack + coalesced dense writes ----
    {
        const int p   = tid & 127;
        const int phw = hw0 + p;
        const int b9  = bidx * NA;
        if (tid < 128) {
            // waves 0-1: conf (f32 planar) + off (bf16x4 interleaved, 8B/anchor)
#pragma unroll
            for (int a = 0; a < 9; ++a) {
                float v0 = so[(5*a+0)*128 + p];
                float v1 = so[(5*a+1)*128 + p];
                float v2 = so[(5*a+2)*128 + p];
                float v3 = so[(5*a+3)*128 + p];
                float v4 = so[(5*a+4)*128 + p];
                int abase = ((b9 + a) << 12) + phw;
                conf_d[abase] = sigf(v0);
                bf16x4 o;
                o[0] = (__bf16)(sigf(v1) - 0.5f);
                o[1] = (__bf16)(sigf(v2) - 0.5f);
                o[2] = (__bf16)v3;
                o[3] = (__bf16)v4;
                *(bf16x4*)(off_w + ((size_t)abase << 2)) = o;
            }
        } else {
            // waves 2-3: cls, full 64B sector per position (pad rows 20..31 = 0)
            unsigned short* dst = cls_w + ((size_t)((bidx << 12) + phw) << 5);
#pragma unroll
            for (int q = 0; q < 4; ++q) {
                bf16x8 v;
#pragma unroll
                for (int r = 0; r < 8; ++r) {
                    int c = q*8 + r;
                    v[r] = (c < 20) ? (__bf16)so[(45 + c)*128 + p] : (__bf16)0.f;
                }
                *(bf16x8*)(dst + q*8) = v;
            }
        }
    }
}

// roles by block range (uniform): [0,2M) conf pos|neg ; [2M,3M) off ; [3M,4M) cls
__global__ void gather_all(const int* __restrict__ pos, const int* __restrict__ neg,
                           const float* __restrict__ conf_d,
                           const unsigned short* __restrict__ off_w,
                           const unsigned short* __restrict__ cls_w,
                           float* __restrict__ out) {
    int t = blockIdx.x * 256 + threadIdx.x;
    if (t < 2*M_) {
        int idx = (t < M_) ? pos[t] : neg[t - M_];
        out[t] = conf_d[idx];
    } else if (t < 3*M_) {
        int i = t - 2*M_;
        int p = pos[i];
        bf16x4 o = *(const bf16x4*)(off_w + ((size_t)p << 2));
        f32x4 f;
        f[0] = (float)o[0]; f[1] = (float)o[1];
        f[2] = (float)o[2]; f[3] = (float)o[3];
        *(f32x4*)(out + 2*(size_t)M_ + 4*(size_t)i) = f;
    } else {
        int i = t - 3*M_;
        int p = pos[i];
        int hw = p & 4095;
        int b  = (p >> 12) / 9;
        const unsigned short* src = cls_w + ((size_t)((b << 12) + hw) << 5);
        float* dst = out + 6*(size_t)M_ + 20*(size_t)i;
        bf16x8 v0 = *(const bf16x8*)(src);
        bf16x8 v1 = *(const bf16x8*)(src + 8);
        bf16x4 v2 = *(const bf16x4*)(src + 16);
        f32x4 f;
        f[0] = (float)v0[0]; f[1] = (float)v0[1]; f[2] = (float)v0[2]; f[3] = (float)v0[3];
        *(f32x4*)(dst) = f;
        f[0] = (float)v0[4]; f[1] = (float)v0[5]; f[2] = (float)v0[6]; f[3] = (float)v0[7];
        *(f32x4*)(dst + 4) = f;
        f[0] = (float)v1[0]; f[1] = (float)v1[1]; f[2] = (float)v1[2]; f[3] = (float)v1[3];
        *(f32x4*)(dst + 8) = f;
        f[0] = (float)v1[4]; f[1] = (float)v1[5]; f[2] = (float)v1[6]; f[3] = (float)v1[7];
        *(f32x4*)(dst + 12) = f;
        f[0] = (float)v2[0]; f[1] = (float)v2[1]; f[2] = (float)v2[2]; f[3] = (float)v2[3];
        *(f32x4*)(dst + 16) = f;
    }
}

extern "C" void kernel_launch(void* const* d_in, const int* in_sizes, int n_in,
                              void* d_out, int out_size, void* d_ws, size_t ws_size,
                              hipStream_t stream) {
    const float* feat = (const float*)d_in[0];
    const float* W1   = (const float*)d_in[1];
    const float* b1   = (const float*)d_in[2];
    const float* W2   = (const float*)d_in[3];
    const float* b2   = (const float*)d_in[4];
    const int*   pos  = (const int*)d_in[5];
    const int*   neg  = (const int*)d_in[6];
    float* out = (float*)d_out;

    char* ws = (char*)d_ws;
    unsigned short* W1bt = (unsigned short*)ws;
    unsigned short* W2p  = (unsigned short*)(ws + 262144);
    float*          conf_d = (float*)(ws + 311296);
    unsigned short* off_w  = (unsigned short*)(ws + 5029888);
    unsigned short* cls_w  = (unsigned short*)(ws + 14467072);

    prep_weights<<<608, 256, 0, stream>>>(W1, W2, W1bt, W2p);
    fused_mlp<<<1024, 256, 0, stream>>>(feat, b1, b2, W1bt, W2p, conf_d, off_w, cls_w);
    gather_all<<<1024, 256, 0, stream>>>(pos, neg, conf_d, off_w, cls_w, out);
}